// Round 14
// baseline (905.183 us; speedup 1.0000x reference)
//
#include <hip/hip_runtime.h>
#include <hip/hip_fp16.h>

typedef _Float16 half_t;
typedef __attribute__((ext_vector_type(8))) _Float16 half8;
typedef __attribute__((ext_vector_type(4))) float f32x4;

#define AS1 __attribute__((address_space(1)))
#define AS3 __attribute__((address_space(3)))

__device__ __forceinline__ void gload16(const half_t* g, half_t* l) {
  __builtin_amdgcn_global_load_lds((const AS1 void*)g, (AS3 void*)l, 16, 0, 0);
}

// ---------------- B-spline basis, UNIFORM grid (h=0.4, knots (j-3)*0.4-1).
__device__ __forceinline__ void bspline8u(float x, float out[8]) {
  float g[12];
#pragma unroll
  for (int j = 0; j < 12; ++j) g[j] = (float)(j - 3) * 0.4f - 1.0f;
  float b[11];
#pragma unroll
  for (int j = 0; j < 11; ++j)
    b[j] = (x >= g[j] && x < g[j + 1]) ? 1.0f : 0.0f;
#pragma unroll
  for (int k = 1; k <= 3; ++k) {
#pragma unroll
    for (int j = 0; j + k < 11; ++j) {
      float rl = 1.0f / (g[j + k] - g[j]);         // constant-folded
      float rr = 1.0f / (g[j + k + 1] - g[j + 1]); // constant-folded
      b[j] = ((x - g[j]) * rl) * b[j] + ((g[j + k + 1] - x) * rr) * b[j + 1];
    }
  }
#pragma unroll
  for (int j = 0; j < 8; ++j) out[j] = b[j];
}

// ---------------- weight conversion: fp32 (base,spline*scaler) -> fp16
__global__ void wconv_kernel(const float* __restrict__ bw, const float* __restrict__ sw,
                             const float* __restrict__ sc, half_t* __restrict__ W,
                             int ibits, int ldw) {
  int idx = blockIdx.x * 256 + threadIdx.x;
  int o = idx >> ibits;
  int i = idx & ((1 << ibits) - 1);
  int c = i >> 10;
  int il = i & 1023;
  float b = bw[idx];
  float scv = sc[idx];
  const float4* svp = (const float4*)sw;
  float4 s0 = svp[(size_t)idx * 2];
  float4 s1 = svp[(size_t)idx * 2 + 1];
  half_t* wrow = W + (size_t)o * ldw + c * 9216;
  wrow[il] = (half_t)b;
  half8 hv;
  hv[0] = (half_t)(s0.x * scv); hv[1] = (half_t)(s0.y * scv);
  hv[2] = (half_t)(s0.z * scv); hv[3] = (half_t)(s0.w * scv);
  hv[4] = (half_t)(s1.x * scv); hv[5] = (half_t)(s1.y * scv);
  hv[6] = (half_t)(s1.z * scv); hv[7] = (half_t)(s1.w * scv);
  *(half8*)&wrow[1024 + il * 8] = hv;
}

// ---------------- activation expansion: v -> [silu(v) | basis(v)[8]] fp16
// Optionally also copies v to xout (fuses the out=x residual baseline).
template <typename ST>
__global__ void expand_kernel(const ST* __restrict__ src, half_t* __restrict__ dst,
                              int Isrc, int i0, int dsub, int kexp,
                              float* __restrict__ xout) {
  int idx = blockIdx.x * 256 + threadIdx.x;
  int n = idx >> 10;
  int il = idx & 1023;
  float v = (float)src[(size_t)n * Isrc + i0 + il];
  float bs[8];
  bspline8u(v, bs);
  half_t* drow = dst + (size_t)n * kexp + (size_t)dsub * 9216;
  drow[il] = (half_t)(v / (1.0f + expf(-v)));
  half8 hb;
#pragma unroll
  for (int k = 0; k < 8; ++k) hb[k] = (half_t)bs[k];
  *(half8*)&drow[1024 + il * 8] = hb;
  if (xout) xout[(size_t)n * Isrc + il] = v;
}

// Single-pass expansion of all 4 layer-2 chunks (fallback modes only).
__global__ void expand4_kernel(const half_t* __restrict__ src, half_t* __restrict__ dst,
                               int ldk2) {
  int idx = blockIdx.x * 256 + threadIdx.x;      // over 4096*4096
  int n = idx >> 12;
  int il4 = idx & 4095;
  int c = il4 >> 10;
  int il = il4 & 1023;
  float v = (float)src[(size_t)n * 4096 + il4];
  float bs[8];
  bspline8u(v, bs);
  half_t* drow = dst + (size_t)n * ldk2 + (size_t)c * 9216;
  drow[il] = (half_t)(v / (1.0f + expf(-v)));
  half8 hb;
#pragma unroll
  for (int k = 0; k < 8; ++k) hb[k] = (half_t)bs[k];
  *(half8*)&drow[1024 + il * 8] = hb;
}

// ---------------- 8-phase 256x256 GEMM — proven-best schedule (round 13).
// MODE 0: gelu->Hout fp16 (ldc=cols); MODE 4: atomicAdd into Cout fp32;
// MODE 5: gelu -> fused KAN expansion into Hout (ldc = padded ldk2 stride).
#define STA(c, t, h)                                                          \
  {                                                                           \
    int r0_ = wid * 8 + (h) * 64;                                             \
    const half_t* g_ = Abase + (size_t)(r0_ + srow) * ldkA +                  \
                       (size_t)(t) * 64 + scol;                               \
    gload16(g_, &As[c][r0_ * 64]);                                            \
    gload16(g_ + (size_t)128 * ldkA, &As[c][(r0_ + 128) * 64]);               \
  }
#define STB(c, t, h)                                                          \
  {                                                                           \
    int r0_ = (wid >> 2) * 64 + (wid & 3) * 8 + (h) * 32;                     \
    const half_t* g_ = Bbase + (size_t)(r0_ + srow) * ldkB +                  \
                       (size_t)(t) * 64 + scol;                               \
    gload16(g_, &Bs[c][r0_ * 64]);                                            \
    gload16(g_ + (size_t)128 * ldkB, &Bs[c][(r0_ + 128) * 64]);               \
  }
#define LOADAF(c, mh)                                                         \
  _Pragma("unroll") for (int a = 0; a < 4; ++a) {                             \
    int row_ = wm * 128 + (mh) * 64 + a * 16 + (lane & 15);                   \
    _Pragma("unroll") for (int ks = 0; ks < 2; ++ks) {                        \
      int ch_ = (ks * 4 + (lane >> 4)) ^ (lane & 7);                          \
      af[a][ks] = *(const half8*)&As[c][row_ * 64 + ch_ * 8];                 \
    }                                                                         \
  }
#define LOADBF(c, nh, bfv)                                                    \
  _Pragma("unroll") for (int b = 0; b < 2; ++b) {                             \
    int row_ = wn * 64 + (nh) * 32 + b * 16 + (lane & 15);                    \
    _Pragma("unroll") for (int ks = 0; ks < 2; ++ks) {                        \
      int ch_ = (ks * 4 + (lane >> 4)) ^ (lane & 7);                          \
      bfv[b][ks] = *(const half8*)&Bs[c][row_ * 64 + ch_ * 8];                \
    }                                                                         \
  }
#define DOPHASE(W, mh, nh, bfv, LOADS, STAGE)                                 \
  do {                                                                        \
    LOADS                                                                     \
    STAGE                                                                     \
    asm volatile("s_waitcnt vmcnt(" #W ")" ::: "memory");                     \
    __builtin_amdgcn_s_barrier();                                             \
    __builtin_amdgcn_sched_barrier(0);                                        \
    __builtin_amdgcn_s_setprio(1);                                            \
    _Pragma("unroll") for (int ks = 0; ks < 2; ++ks)                          \
      _Pragma("unroll") for (int a = 0; a < 4; ++a)                           \
        _Pragma("unroll") for (int b = 0; b < 2; ++b)                         \
          acc[(mh) * 4 + a][(nh) * 2 + b] =                                   \
              __builtin_amdgcn_mfma_f32_16x16x32_f16(                         \
                  af[a][ks], bfv[b][ks], acc[(mh) * 4 + a][(nh) * 2 + b],     \
                  0, 0, 0);                                                   \
    __builtin_amdgcn_s_setprio(0);                                            \
    __builtin_amdgcn_s_barrier();                                             \
    __builtin_amdgcn_sched_barrier(0);                                        \
  } while (0)

template <int MODE>
__global__ __launch_bounds__(512, 2) void gemm8_kernel(
    const half_t* __restrict__ A, const half_t* __restrict__ B,
    int ldkA, int ldkB, int kzLen,
    float* __restrict__ Cout, half_t* __restrict__ Hout, int ldc) {
  __shared__ __align__(16) half_t As[2][256 * 64];
  __shared__ __align__(16) half_t Bs[2][256 * 64];

  const int tid = threadIdx.x;
  const int wid = tid >> 6;
  const int lane = tid & 63;
  const int wm = wid >> 2;
  const int wn = wid & 3;

  const half_t* Abase = A + (size_t)blockIdx.x * 256 * ldkA +
                        (size_t)blockIdx.z * kzLen;
  const half_t* Bbase = B + (size_t)blockIdx.y * 256 * ldkB +
                        (size_t)blockIdx.z * kzLen;

  const int srow = lane >> 3;                    // row within 8-row region
  const int scol = ((lane & 7) ^ srow) * 8;      // pre-swizzled 16B chunk

  const int nt = kzLen >> 6;                     // K-tiles (BK=64), even, >=4

  f32x4 acc[8][4] = {};
  half8 af[4][2], bA[2][2], bB[2][2];

  // Prologue: tile0 complete + tile1 {Am0,Bn0}; drain; barrier.
  STA(0, 0, 0); STB(0, 0, 0); STB(0, 0, 1); STA(0, 0, 1);
  STA(1, 1, 0); STB(1, 1, 0);
  asm volatile("s_waitcnt vmcnt(0)" ::: "memory");
  __builtin_amdgcn_s_barrier();
  __builtin_amdgcn_sched_barrier(0);

  for (int i = 0; i < (nt >> 1) - 1; ++i) {
    const int t = 2 * i;
    DOPHASE(6, 0, 0, bA, { LOADAF(0, 0) LOADBF(0, 0, bA) }, { STB(1, t + 1, 1); });
    DOPHASE(6, 0, 1, bB, { LOADBF(0, 1, bB) },              { STA(1, t + 1, 1); });
    DOPHASE(6, 1, 1, bB, { LOADAF(0, 1) },                  { STA(0, t + 2, 0); });
    DOPHASE(6, 1, 0, bA, {},                                { STB(0, t + 2, 0); });
    DOPHASE(6, 0, 0, bA, { LOADAF(1, 0) LOADBF(1, 0, bA) }, { STB(0, t + 2, 1); });
    DOPHASE(6, 0, 1, bB, { LOADBF(1, 1, bB) },              { STA(0, t + 2, 1); });
    DOPHASE(6, 1, 1, bB, { LOADAF(1, 1) },                  { STA(1, t + 3, 0); });
    DOPHASE(6, 1, 0, bA, {},                                { STB(1, t + 3, 0); });
  }
  {
    const int t = nt - 2;  // tail: stages only t+1's remaining halves
    DOPHASE(6, 0, 0, bA, { LOADAF(0, 0) LOADBF(0, 0, bA) }, { STB(1, t + 1, 1); });
    DOPHASE(6, 0, 1, bB, { LOADBF(0, 1, bB) },              { STA(1, t + 1, 1); });
    DOPHASE(6, 1, 1, bB, { LOADAF(0, 1) },                  {});
    DOPHASE(6, 1, 0, bA, {},                                {});
    DOPHASE(4, 0, 0, bA, { LOADAF(1, 0) LOADBF(1, 0, bA) }, {});
    DOPHASE(2, 0, 1, bB, { LOADBF(1, 1, bB) },              {});
    DOPHASE(0, 1, 1, bB, { LOADAF(1, 1) },                  {});
    DOPHASE(0, 1, 0, bA, {},                                {});
  }

  const int r_lo = (lane >> 4) << 2;
  const int col0 = (int)blockIdx.y * 256 + wn * 64 + (lane & 15);
  const int row00 = (int)blockIdx.x * 256 + wm * 128 + r_lo;
#pragma unroll
  for (int mf = 0; mf < 8; ++mf)
#pragma unroll
    for (int nf = 0; nf < 4; ++nf)
#pragma unroll
      for (int j = 0; j < 4; ++j) {
        float v = acc[mf][nf][j];
        if constexpr (MODE == 0) {
          size_t off = (size_t)(row00 + mf * 16 + j) * ldc + col0 + nf * 16;
          v = 0.5f * v * (1.0f + erff(v * 0.70710678118654752f));
          Hout[off] = (half_t)v;
        } else if constexpr (MODE == 5) {
          v = 0.5f * v * (1.0f + erff(v * 0.70710678118654752f));
          int s = col0 + nf * 16;                 // source feature 0..4095
          int cc = s >> 10, il = s & 1023;
          half_t* drow = Hout + (size_t)(row00 + mf * 16 + j) * ldc +
                         (size_t)cc * 9216;
          drow[il] = (half_t)(v / (1.0f + expf(-v)));
          float bs[8];
          bspline8u(v, bs);
          half8 hb;
#pragma unroll
          for (int k = 0; k < 8; ++k) hb[k] = (half_t)bs[k];
          *(half8*)&drow[1024 + il * 8] = hb;
        } else {
          size_t off = (size_t)(row00 + mf * 16 + j) * ldc + col0 + nf * 16;
          atomicAdd(&Cout[off], v);
        }
      }
}

extern "C" void kernel_launch(void* const* d_in, const int* in_sizes, int n_in,
                              void* d_out, int out_size, void* d_ws, size_t ws_size,
                              hipStream_t stream) {
  const float* x   = (const float*)d_in[0];
  const float* bw1 = (const float*)d_in[1];
  const float* sw1 = (const float*)d_in[2];
  const float* sc1 = (const float*)d_in[3];
  const float* bw2 = (const float*)d_in[4];
  const float* sw2 = (const float*)d_in[5];
  const float* sc2 = (const float*)d_in[6];
  float* out = (float*)d_out;

  const int LDK1 = 9216 + 64;
  const int LDK2 = 36864 + 64;
  const int LDK2H = 18432 + 64;

  half_t* Wbuf = (half_t*)d_ws;
  const size_t W_HALVES  = (size_t)4096 * LDK1;   // W1 region (W2 reuses it)
  const size_t A1_HALVES = (size_t)4096 * LDK1;   // layer-1 expanded A
  const size_t AF_HALVES = (size_t)4096 * LDK2;   // layer-2 expanded A
  const size_t A2_HALVES = (size_t)4096 * LDK2H;
  const size_t HH_HALVES = (size_t)4096 * 4096;
  // Fused mode needs W + A1 + AF (A1 and AF disjoint: gemm1 reads A1 while
  // its epilogue writes AF).
  int mode = 1;
  if (ws_size >= (W_HALVES + A1_HALVES + AF_HALVES) * sizeof(half_t))
    mode = 4;
  else if (ws_size >= (W_HALVES + A1_HALVES + A2_HALVES + HH_HALVES) * sizeof(half_t))
    mode = 2;
  half_t* Abuf = Wbuf + W_HALVES;        // layer-1 A (LDK1 rows)
  half_t* A2exp = Abuf + A1_HALVES;      // layer-2 A (mode 4: LDK2 rows;
                                         // mode 2: LDK2H rows)
  half_t* Hh = A2exp + (mode == 4 ? AF_HALVES
                        : mode == 2 ? A2_HALVES : 0);  // fallback h buffer

  const int T = 256;
  const int NB = (4096 * 1024) / T;

  // ---- layer 1 (expand1 also writes out = x, the residual baseline) ----
  wconv_kernel<<<NB, T, 0, stream>>>(bw1, sw1, sc1, Wbuf, 10, LDK1);
  expand_kernel<float><<<NB, T, 0, stream>>>(x, Abuf, 1024, 0, 0, LDK1, out);

  if (mode == 4) {
    // gemm1 epilogue fuses gelu + layer-2 expansion straight into A2exp.
    gemm8_kernel<5><<<dim3(16, 16, 1), 512, 0, stream>>>(
        Abuf, Wbuf, LDK1, LDK1, 9216, nullptr, A2exp, LDK2);
    wconv_kernel<<<NB, T, 0, stream>>>(bw2, sw2, sc2, Wbuf, 12, LDK2);
    gemm8_kernel<4><<<dim3(16, 4, 4), 512, 0, stream>>>(
        A2exp, Wbuf, LDK2, LDK2, 9216, out, nullptr, 1024);
  } else if (mode == 2) {
    gemm8_kernel<0><<<dim3(16, 16, 1), 512, 0, stream>>>(
        Abuf, Wbuf, LDK1, LDK1, 9216, nullptr, Hh, 4096);
    wconv_kernel<<<NB, T, 0, stream>>>(bw2, sw2, sc2, Wbuf, 12, LDK2);
    for (int c = 0; c < 2; ++c) {
      expand_kernel<half_t><<<NB, T, 0, stream>>>(Hh, A2exp, 4096, c * 2048, 0, LDK2H, nullptr);
      expand_kernel<half_t><<<NB, T, 0, stream>>>(Hh, A2exp, 4096, c * 2048 + 1024, 1, LDK2H, nullptr);
      gemm8_kernel<4><<<dim3(16, 4, 4), 512, 0, stream>>>(
          A2exp, Wbuf + (size_t)c * 18432, LDK2H, LDK2, 4608, out, nullptr, 1024);
    }
  } else {
    // 1-chunk fallback: reuse Abuf region for each layer-2 chunk.
    half_t* HhF = A2exp;  // h buffer right after A1
    gemm8_kernel<0><<<dim3(16, 16, 1), 512, 0, stream>>>(
        Abuf, Wbuf, LDK1, LDK1, 9216, nullptr, HhF, 4096);
    wconv_kernel<<<NB, T, 0, stream>>>(bw2, sw2, sc2, Wbuf, 12, LDK2);
    for (int c = 0; c < 4; ++c) {
      expand_kernel<half_t><<<NB, T, 0, stream>>>(HhF, Abuf, 4096, c * 1024, 0, LDK1, nullptr);
      gemm8_kernel<4><<<dim3(16, 4, 4), 512, 0, stream>>>(
          Abuf, Wbuf + (size_t)c * 9216, LDK1, LDK2, 2304, out, nullptr, 1024);
    }
  }
}

// Round 15
// 799.061 us; speedup vs baseline: 1.1328x; 1.1328x over previous
//
#include <hip/hip_runtime.h>
#include <hip/hip_fp16.h>

typedef _Float16 half_t;
typedef __attribute__((ext_vector_type(8))) _Float16 half8;
typedef __attribute__((ext_vector_type(4))) float f32x4;

#define AS1 __attribute__((address_space(1)))
#define AS3 __attribute__((address_space(3)))

__device__ __forceinline__ void gload16(const half_t* g, half_t* l) {
  __builtin_amdgcn_global_load_lds((const AS1 void*)g, (AS3 void*)l, 16, 0, 0);
}

// ---------------- B-spline basis, UNIFORM grid (h=0.4, knots (j-3)*0.4-1).
__device__ __forceinline__ void bspline8u(float x, float out[8]) {
  float g[12];
#pragma unroll
  for (int j = 0; j < 12; ++j) g[j] = (float)(j - 3) * 0.4f - 1.0f;
  float b[11];
#pragma unroll
  for (int j = 0; j < 11; ++j)
    b[j] = (x >= g[j] && x < g[j + 1]) ? 1.0f : 0.0f;
#pragma unroll
  for (int k = 1; k <= 3; ++k) {
#pragma unroll
    for (int j = 0; j + k < 11; ++j) {
      float rl = 1.0f / (g[j + k] - g[j]);         // constant-folded
      float rr = 1.0f / (g[j + k + 1] - g[j + 1]); // constant-folded
      b[j] = ((x - g[j]) * rl) * b[j] + ((g[j + k + 1] - x) * rr) * b[j + 1];
    }
  }
#pragma unroll
  for (int j = 0; j < 8; ++j) out[j] = b[j];
}

// ---------------- weight conversion: fp32 (base,spline*scaler) -> fp16
__global__ void wconv_kernel(const float* __restrict__ bw, const float* __restrict__ sw,
                             const float* __restrict__ sc, half_t* __restrict__ W,
                             int ibits, int ldw) {
  int idx = blockIdx.x * 256 + threadIdx.x;
  int o = idx >> ibits;
  int i = idx & ((1 << ibits) - 1);
  int c = i >> 10;
  int il = i & 1023;
  float b = bw[idx];
  float scv = sc[idx];
  const float4* svp = (const float4*)sw;
  float4 s0 = svp[(size_t)idx * 2];
  float4 s1 = svp[(size_t)idx * 2 + 1];
  half_t* wrow = W + (size_t)o * ldw + c * 9216;
  wrow[il] = (half_t)b;
  half8 hv;
  hv[0] = (half_t)(s0.x * scv); hv[1] = (half_t)(s0.y * scv);
  hv[2] = (half_t)(s0.z * scv); hv[3] = (half_t)(s0.w * scv);
  hv[4] = (half_t)(s1.x * scv); hv[5] = (half_t)(s1.y * scv);
  hv[6] = (half_t)(s1.z * scv); hv[7] = (half_t)(s1.w * scv);
  *(half8*)&wrow[1024 + il * 8] = hv;
}

// ---------------- activation expansion: v -> [silu(v) | basis(v)[8]] fp16
// Optionally also copies v to xout (fuses the out=x residual baseline).
// Scalar layout: lane-adjacent 16B spline stores = fully coalesced.
template <typename ST>
__global__ void expand_kernel(const ST* __restrict__ src, half_t* __restrict__ dst,
                              int Isrc, int i0, int dsub, int kexp,
                              float* __restrict__ xout) {
  int idx = blockIdx.x * 256 + threadIdx.x;
  int n = idx >> 10;
  int il = idx & 1023;
  float v = (float)src[(size_t)n * Isrc + i0 + il];
  float bs[8];
  bspline8u(v, bs);
  half_t* drow = dst + (size_t)n * kexp + (size_t)dsub * 9216;
  drow[il] = (half_t)(v / (1.0f + expf(-v)));
  half8 hb;
#pragma unroll
  for (int k = 0; k < 8; ++k) hb[k] = (half_t)bs[k];
  *(half8*)&drow[1024 + il * 8] = hb;
  if (xout) xout[(size_t)n * Isrc + il] = v;
}

// Single-pass expansion of all 4 layer-2 chunks (reads Hh once).
__global__ void expand4_kernel(const half_t* __restrict__ src, half_t* __restrict__ dst,
                               int ldk2) {
  int idx = blockIdx.x * 256 + threadIdx.x;      // over 4096*4096
  int n = idx >> 12;
  int il4 = idx & 4095;
  int c = il4 >> 10;
  int il = il4 & 1023;
  float v = (float)src[(size_t)n * 4096 + il4];
  float bs[8];
  bspline8u(v, bs);
  half_t* drow = dst + (size_t)n * ldk2 + (size_t)c * 9216;
  drow[il] = (half_t)(v / (1.0f + expf(-v)));
  half8 hb;
#pragma unroll
  for (int k = 0; k < 8; ++k) hb[k] = (half_t)bs[k];
  *(half8*)&drow[1024 + il * 8] = hb;
}

// ---------------- 8-phase 256x256 GEMM — the proven-best schedule.
// Gray-code quadrant order with persistent frag regs (24 ds_read_b128 per
// K-tile/wave), per-phase vmcnt(6) pacing, 2 barriers/phase, peeled tail
// with exact counted waits 6,6,6,6,4,2,0,0. Variant bracket (rounds 6-14):
// this config 345us gemm2; VM8 358; even-reads 369; 2-point-vmcnt 385;
// 1-barrier 395; reg-dbuf spills; epilogue-fused expansion 490+. The
// residual vs m201's 62% MfmaUtil sits behind the 128-arch-VGPR cap
// (1 block/CU, acc=128 AGPR) — not reachable at this tile/LDS envelope.
#define STA(c, t, h)                                                          \
  {                                                                           \
    int r0_ = wid * 8 + (h) * 64;                                             \
    const half_t* g_ = Abase + (size_t)(r0_ + srow) * ldkA +                  \
                       (size_t)(t) * 64 + scol;                               \
    gload16(g_, &As[c][r0_ * 64]);                                            \
    gload16(g_ + (size_t)128 * ldkA, &As[c][(r0_ + 128) * 64]);               \
  }
#define STB(c, t, h)                                                          \
  {                                                                           \
    int r0_ = (wid >> 2) * 64 + (wid & 3) * 8 + (h) * 32;                     \
    const half_t* g_ = Bbase + (size_t)(r0_ + srow) * ldkB +                  \
                       (size_t)(t) * 64 + scol;                               \
    gload16(g_, &Bs[c][r0_ * 64]);                                            \
    gload16(g_ + (size_t)128 * ldkB, &Bs[c][(r0_ + 128) * 64]);               \
  }
#define LOADAF(c, mh)                                                         \
  _Pragma("unroll") for (int a = 0; a < 4; ++a) {                             \
    int row_ = wm * 128 + (mh) * 64 + a * 16 + (lane & 15);                   \
    _Pragma("unroll") for (int ks = 0; ks < 2; ++ks) {                        \
      int ch_ = (ks * 4 + (lane >> 4)) ^ (lane & 7);                          \
      af[a][ks] = *(const half8*)&As[c][row_ * 64 + ch_ * 8];                 \
    }                                                                         \
  }
#define LOADBF(c, nh, bfv)                                                    \
  _Pragma("unroll") for (int b = 0; b < 2; ++b) {                             \
    int row_ = wn * 64 + (nh) * 32 + b * 16 + (lane & 15);                    \
    _Pragma("unroll") for (int ks = 0; ks < 2; ++ks) {                        \
      int ch_ = (ks * 4 + (lane >> 4)) ^ (lane & 7);                          \
      bfv[b][ks] = *(const half8*)&Bs[c][row_ * 64 + ch_ * 8];                \
    }                                                                         \
  }
#define DOPHASE(W, mh, nh, bfv, LOADS, STAGE)                                 \
  do {                                                                        \
    LOADS                                                                     \
    STAGE                                                                     \
    asm volatile("s_waitcnt vmcnt(" #W ")" ::: "memory");                     \
    __builtin_amdgcn_s_barrier();                                             \
    __builtin_amdgcn_sched_barrier(0);                                        \
    __builtin_amdgcn_s_setprio(1);                                            \
    _Pragma("unroll") for (int ks = 0; ks < 2; ++ks)                          \
      _Pragma("unroll") for (int a = 0; a < 4; ++a)                           \
        _Pragma("unroll") for (int b = 0; b < 2; ++b)                         \
          acc[(mh) * 4 + a][(nh) * 2 + b] =                                   \
              __builtin_amdgcn_mfma_f32_16x16x32_f16(                         \
                  af[a][ks], bfv[b][ks], acc[(mh) * 4 + a][(nh) * 2 + b],     \
                  0, 0, 0);                                                   \
    __builtin_amdgcn_s_setprio(0);                                            \
    __builtin_amdgcn_s_barrier();                                             \
    __builtin_amdgcn_sched_barrier(0);                                        \
  } while (0)

template <int MODE>
__global__ __launch_bounds__(512, 2) void gemm8_kernel(
    const half_t* __restrict__ A, const half_t* __restrict__ B,
    int ldkA, int ldkB, int kzLen,
    float* __restrict__ Cout, half_t* __restrict__ Hout, int ldc) {
  __shared__ __align__(16) half_t As[2][256 * 64];
  __shared__ __align__(16) half_t Bs[2][256 * 64];

  const int tid = threadIdx.x;
  const int wid = tid >> 6;
  const int lane = tid & 63;
  const int wm = wid >> 2;
  const int wn = wid & 3;

  const half_t* Abase = A + (size_t)blockIdx.x * 256 * ldkA +
                        (size_t)blockIdx.z * kzLen;
  const half_t* Bbase = B + (size_t)blockIdx.y * 256 * ldkB +
                        (size_t)blockIdx.z * kzLen;

  const int srow = lane >> 3;                    // row within 8-row region
  const int scol = ((lane & 7) ^ srow) * 8;      // pre-swizzled 16B chunk

  const int nt = kzLen >> 6;                     // K-tiles (BK=64), even, >=4

  f32x4 acc[8][4] = {};
  half8 af[4][2], bA[2][2], bB[2][2];

  // Prologue: tile0 complete + tile1 {Am0,Bn0}; drain; barrier.
  STA(0, 0, 0); STB(0, 0, 0); STB(0, 0, 1); STA(0, 0, 1);
  STA(1, 1, 0); STB(1, 1, 0);
  asm volatile("s_waitcnt vmcnt(0)" ::: "memory");
  __builtin_amdgcn_s_barrier();
  __builtin_amdgcn_sched_barrier(0);

  for (int i = 0; i < (nt >> 1) - 1; ++i) {
    const int t = 2 * i;
    DOPHASE(6, 0, 0, bA, { LOADAF(0, 0) LOADBF(0, 0, bA) }, { STB(1, t + 1, 1); });
    DOPHASE(6, 0, 1, bB, { LOADBF(0, 1, bB) },              { STA(1, t + 1, 1); });
    DOPHASE(6, 1, 1, bB, { LOADAF(0, 1) },                  { STA(0, t + 2, 0); });
    DOPHASE(6, 1, 0, bA, {},                                { STB(0, t + 2, 0); });
    DOPHASE(6, 0, 0, bA, { LOADAF(1, 0) LOADBF(1, 0, bA) }, { STB(0, t + 2, 1); });
    DOPHASE(6, 0, 1, bB, { LOADBF(1, 1, bB) },              { STA(0, t + 2, 1); });
    DOPHASE(6, 1, 1, bB, { LOADAF(1, 1) },                  { STA(1, t + 3, 0); });
    DOPHASE(6, 1, 0, bA, {},                                { STB(1, t + 3, 0); });
  }
  {
    const int t = nt - 2;  // tail: stages only t+1's remaining halves
    DOPHASE(6, 0, 0, bA, { LOADAF(0, 0) LOADBF(0, 0, bA) }, { STB(1, t + 1, 1); });
    DOPHASE(6, 0, 1, bB, { LOADBF(0, 1, bB) },              { STA(1, t + 1, 1); });
    DOPHASE(6, 1, 1, bB, { LOADAF(0, 1) },                  {});
    DOPHASE(6, 1, 0, bA, {},                                {});
    DOPHASE(4, 0, 0, bA, { LOADAF(1, 0) LOADBF(1, 0, bA) }, {});
    DOPHASE(2, 0, 1, bB, { LOADBF(1, 1, bB) },              {});
    DOPHASE(0, 1, 1, bB, { LOADAF(1, 1) },                  {});
    DOPHASE(0, 1, 0, bA, {},                                {});
  }

  const int r_lo = (lane >> 4) << 2;
  const int col0 = (int)blockIdx.y * 256 + wn * 64 + (lane & 15);
  const int row00 = (int)blockIdx.x * 256 + wm * 128 + r_lo;
#pragma unroll
  for (int mf = 0; mf < 8; ++mf)
#pragma unroll
    for (int nf = 0; nf < 4; ++nf)
#pragma unroll
      for (int j = 0; j < 4; ++j) {
        float v = acc[mf][nf][j];
        size_t off = (size_t)(row00 + mf * 16 + j) * ldc + col0 + nf * 16;
        if constexpr (MODE == 0) {
          v = 0.5f * v * (1.0f + erff(v * 0.70710678118654752f));
          Hout[off] = (half_t)v;
        } else {
          atomicAdd(&Cout[off], v);
        }
      }
}

extern "C" void kernel_launch(void* const* d_in, const int* in_sizes, int n_in,
                              void* d_out, int out_size, void* d_ws, size_t ws_size,
                              hipStream_t stream) {
  const float* x   = (const float*)d_in[0];
  const float* bw1 = (const float*)d_in[1];
  const float* sw1 = (const float*)d_in[2];
  const float* sc1 = (const float*)d_in[3];
  const float* bw2 = (const float*)d_in[4];
  const float* sw2 = (const float*)d_in[5];
  const float* sc2 = (const float*)d_in[6];
  float* out = (float*)d_out;

  const int LDK1 = 9216 + 64;
  const int LDK2 = 36864 + 64;
  const int LDK2H = 18432 + 64;

  half_t* Wbuf = (half_t*)d_ws;
  const size_t W_HALVES  = (size_t)4096 * LDK1;
  const size_t AF_HALVES = (size_t)4096 * LDK2;
  const size_t A2_HALVES = (size_t)4096 * LDK2H;
  const size_t A1_HALVES = (size_t)4096 * LDK1;
  const size_t HH_HALVES = (size_t)4096 * 4096;
  int abuf_chunks = 1;
  if (ws_size >= (W_HALVES + AF_HALVES + HH_HALVES) * sizeof(half_t))
    abuf_chunks = 4;
  else if (ws_size >= (W_HALVES + A2_HALVES + HH_HALVES) * sizeof(half_t))
    abuf_chunks = 2;
  half_t* Abuf = Wbuf + W_HALVES;
  half_t* Hh   = Abuf + (abuf_chunks == 4 ? AF_HALVES
                         : abuf_chunks == 2 ? A2_HALVES : A1_HALVES);

  const int T = 256;
  const int NB = (4096 * 1024) / T;

  // ---- layer 1 (expand1 also writes out = x, the residual baseline) ----
  wconv_kernel<<<NB, T, 0, stream>>>(bw1, sw1, sc1, Wbuf, 10, LDK1);
  expand_kernel<float><<<NB, T, 0, stream>>>(x, Abuf, 1024, 0, 0, LDK1, out);
  gemm8_kernel<0><<<dim3(16, 16, 1), 512, 0, stream>>>(
      Abuf, Wbuf, LDK1, LDK1, 9216, nullptr, Hh, 4096);

  // ---- layer 2: W2 rows [o][LDK2], data K-contiguous in [0,36864) ----
  wconv_kernel<<<NB, T, 0, stream>>>(bw2, sw2, sc2, Wbuf, 12, LDK2);
  if (abuf_chunks == 4) {
    expand4_kernel<<<4 * NB, T, 0, stream>>>(Hh, Abuf, LDK2);
    gemm8_kernel<4><<<dim3(16, 4, 4), 512, 0, stream>>>(
        Abuf, Wbuf, LDK2, LDK2, 9216, out, nullptr, 1024);
  } else if (abuf_chunks == 2) {
    for (int c = 0; c < 2; ++c) {
      expand_kernel<half_t><<<NB, T, 0, stream>>>(Hh, Abuf, 4096, c * 2048, 0, LDK2H, nullptr);
      expand_kernel<half_t><<<NB, T, 0, stream>>>(Hh, Abuf, 4096, c * 2048 + 1024, 1, LDK2H, nullptr);
      gemm8_kernel<4><<<dim3(16, 4, 4), 512, 0, stream>>>(
          Abuf, Wbuf + (size_t)c * 18432, LDK2H, LDK2, 4608, out, nullptr, 1024);
    }
  } else {
    for (int c = 0; c < 4; ++c) {
      expand_kernel<half_t><<<NB, T, 0, stream>>>(Hh, Abuf, 4096, c * 1024, 0, LDK1, nullptr);
      gemm8_kernel<4><<<dim3(16, 4, 4), 512, 0, stream>>>(
          Abuf, Wbuf + (size_t)c * 9216, LDK1, LDK2, 2304, out, nullptr, 1024);
    }
  }
}